// Round 6
// baseline (1567.852 us; speedup 1.0000x reference)
//
#include <hip/hip_runtime.h>
#include <stdint.h>

// softmax((x@q)@(x@k)) @ (x@v), N=2048, fp32 in/out.
// R6: occupancy attack. K-split x4 (grid 1024 = 4 blocks/CU, 16 waves/CU) so
// independent blocks overlap read/MFMA phases; staging via global_load_lds DMA
// (no VGPR round trip, no ds_write instructions, frees ~32 VGPRs) into the
// lane-linear LDS layout (slot==lane; wave-uniform base + lane*16 = DMA pattern;
// 0 bank conflicts, verified R4/R5). Single 32KB buffer, m97-style 2-barrier
// K-loop, 16 steps/block. Numerics unchanged: fp16 2-term split, 3 products
// (t0t0 + 2^-12*(t0t1'+t1't0)), atomicAdd f32 into zeroed targets.

#define TN 2048

typedef float f32x4 __attribute__((ext_vector_type(4)));
typedef _Float16 f16;
typedef f16 f16x8 __attribute__((ext_vector_type(8)));
typedef f16 f16x4 __attribute__((ext_vector_type(4)));

#define MFMA16(a, b, c) __builtin_amdgcn_mfma_f32_16x16x32_f16(a, b, c, 0, 0, 0)

// async global->LDS DMA, 16B/lane; HW scatters lane i to ldsbase + i*16
__device__ __forceinline__ void gll16(const f16* g, f16* l) {
    __builtin_amdgcn_global_load_lds(
        (const __attribute__((address_space(1))) unsigned int*)g,
        (__attribute__((address_space(3))) unsigned int*)l, 16, 0, 0);
}

// ---------------- split kernels: a ~= t0 + t1'/4096 ----------------
__global__ void split2_kernel(const float* __restrict__ in,
                              f16* __restrict__ t0, f16* __restrict__ t1) {
    int i = (blockIdx.x * 256 + threadIdx.x) * 4;
    f32x4 f = *(const f32x4*)(in + i);
    f16x4 o0, o1;
#pragma unroll
    for (int e = 0; e < 4; ++e) {
        float a = f[e];
        f16 h0 = (f16)a;
        float r = (a - (float)h0) * 4096.f;
        o0[e] = h0; o1[e] = (f16)r;
    }
    *(f16x4*)(t0 + i) = o0; *(f16x4*)(t1 + i) = o1;
}

__global__ void split2t_kernel(const float* __restrict__ in,
                               f16* __restrict__ t0, f16* __restrict__ t1) {
    __shared__ f16 s0[64][68], s1[64][68];
    int bc = blockIdx.x * 64, br = blockIdx.y * 64;
    int tx = threadIdx.x & 15, ty = threadIdx.x >> 4;
#pragma unroll
    for (int rr = 0; rr < 64; rr += 16) {
        int r = rr + ty;
        f32x4 f = *(const f32x4*)(in + (size_t)(br + r) * TN + bc + tx * 4);
#pragma unroll
        for (int e = 0; e < 4; ++e) {
            float a = f[e];
            f16 h0 = (f16)a;
            float rr2 = (a - (float)h0) * 4096.f;
            s0[tx * 4 + e][r] = h0; s1[tx * 4 + e][r] = (f16)rr2;
        }
    }
    __syncthreads();
#pragma unroll
    for (int rr = 0; rr < 64; rr += 16) {
        int c = rr + ty;
        f16x4 o0, o1;
#pragma unroll
        for (int e = 0; e < 4; ++e) { o0[e] = s0[c][tx*4+e]; o1[e] = s1[c][tx*4+e]; }
        size_t off = (size_t)(bc + c) * TN + br + tx * 4;
        *(f16x4*)(t0 + off) = o0; *(f16x4*)(t1 + off) = o1;
    }
}

__global__ void cast1t_kernel(const float* __restrict__ in, f16* __restrict__ t0) {
    __shared__ f16 s0[64][68];
    int bc = blockIdx.x * 64, br = blockIdx.y * 64;
    int tx = threadIdx.x & 15, ty = threadIdx.x >> 4;
#pragma unroll
    for (int rr = 0; rr < 64; rr += 16) {
        int r = rr + ty;
        f32x4 f = *(const f32x4*)(in + (size_t)(br + r) * TN + bc + tx * 4);
#pragma unroll
        for (int e = 0; e < 4; ++e) s0[tx * 4 + e][r] = (f16)f[e];
    }
    __syncthreads();
#pragma unroll
    for (int rr = 0; rr < 64; rr += 16) {
        int c = rr + ty;
        f16x4 o0;
#pragma unroll
        for (int e = 0; e < 4; ++e) o0[e] = s0[c][tx*4+e];
        *(f16x4*)(t0 + (size_t)(bc + c) * TN + br + tx * 4) = o0;
    }
}

// ---------------- 3-product split GEMM, 128x128, K-split x4, DMA staging ----------------
// LDS: 32 segments x 1KB (32 KB). Segs 0-7: a0, 8-15: a1, 16-23: b0, 24-31: b1.
// Segment slot s holds (row=s&15, kchunk=s>>4); DMA lane i fetches exactly that
// (src row += lane&15, src k += (lane>>4)*8) and HW lands it at slot i.
// Frag-read lane reads slot==lane. Lane-linear both ways: 0 conflicts.
__global__ __launch_bounds__(256, 4) void gemm3_f16(
    const f16* __restrict__ a0p, const f16* __restrict__ a1p,
    const f16* __restrict__ b0p, const f16* __restrict__ b1p,
    float* __restrict__ C) {
    __shared__ f16 lds[32 * 512];  // 32 KB
    const int tid = threadIdx.x;
    const int wave = tid >> 6, lane = tid & 63;
    const int wr = (wave >> 1) * 64, wc = (wave & 1) * 64;
    const int quad = lane >> 4, l16 = lane & 15;
    const int bm = blockIdx.y * 128, bn = blockIdx.x * 128;
    const int kbase = blockIdx.z * 512;

    // per-lane global srcs for the 8 segments this wave stages
    const f16* sp[8];
#pragma unroll
    for (int t = 0; t < 8; ++t) {
        int s = wave * 8 + t;
        const f16* base; int gr;
        if (s < 16) { base = (s & 8) ? a1p : a0p; gr = bm + (s & 7) * 16 + l16; }
        else        { base = (s & 8) ? b1p : b0p; gr = bn + (s & 7) * 16 + l16; }
        sp[t] = base + (size_t)gr * TN + kbase + quad * 8;
    }
    f16* dseg = lds + wave * 8 * 512;   // wave-uniform DMA dest base
    const f16* rdb = lds + lane * 8;    // frag-read base (slot==lane)

    f32x4 acc1[4][4], acc2[4][4];
#pragma unroll
    for (int i = 0; i < 4; ++i)
#pragma unroll
        for (int j = 0; j < 4; ++j) {
            acc1[i][j] = (f32x4){0.f, 0.f, 0.f, 0.f};
            acc2[i][j] = (f32x4){0.f, 0.f, 0.f, 0.f};
        }

    for (int step = 0; step < 16; ++step) {
        __syncthreads();   // prior step's frag reads done -> LDS writable
#pragma unroll
        for (int t = 0; t < 8; ++t) { gll16(sp[t], dseg + t * 512); sp[t] += 32; }
        __syncthreads();   // drains vmcnt -> staged tile visible

        f16x8 b0f[4], b1f[4], a0f[4], a1f[4];
#pragma unroll
        for (int j = 0; j < 4; ++j) {
            b0f[j] = *(const f16x8*)(rdb + (16 + (wc >> 4) + j) * 512);
            b1f[j] = *(const f16x8*)(rdb + (24 + (wc >> 4) + j) * 512);
        }
#pragma unroll
        for (int i = 0; i < 4; ++i) {
            a0f[i] = *(const f16x8*)(rdb + ((wr >> 4) + i) * 512);
            a1f[i] = *(const f16x8*)(rdb + (8 + (wr >> 4) + i) * 512);
        }
#pragma unroll
        for (int i = 0; i < 4; ++i)
#pragma unroll
            for (int j = 0; j < 4; ++j) {
                acc1[i][j] = MFMA16(a0f[i], b0f[j], acc1[i][j]);
                acc2[i][j] = MFMA16(a0f[i], b1f[j], acc2[i][j]);
                acc2[i][j] = MFMA16(a1f[i], b0f[j], acc2[i][j]);
            }
    }
    const float sc = 1.f / 4096.f;
#pragma unroll
    for (int i = 0; i < 4; ++i)
#pragma unroll
        for (int j = 0; j < 4; ++j) {
            int row = bm + wr + i * 16 + quad * 4;
            int col = bn + wc + j * 16 + l16;
            float* p = C + (size_t)row * TN + col;
#pragma unroll
            for (int r = 0; r < 4; ++r)
                atomicAdd(p + (size_t)r * TN, acc1[i][j][r] + acc2[i][j][r] * sc);
        }
}

// ---------------- single-product GEMM, same structure ----------------
__global__ __launch_bounds__(256, 4) void gemm1_f16(
    const f16* __restrict__ A, const f16* __restrict__ Bt,
    float* __restrict__ C) {
    __shared__ f16 lds[16 * 512];  // 16 KB
    const int tid = threadIdx.x;
    const int wave = tid >> 6, lane = tid & 63;
    const int wr = (wave >> 1) * 64, wc = (wave & 1) * 64;
    const int quad = lane >> 4, l16 = lane & 15;
    const int bm = blockIdx.y * 128, bn = blockIdx.x * 128;
    const int kbase = blockIdx.z * 512;

    const f16* sp[4];
#pragma unroll
    for (int t = 0; t < 4; ++t) {
        int s = wave * 4 + t;
        const f16* base; int gr;
        if (s < 8) { base = A;  gr = bm + s * 16 + l16; }
        else       { base = Bt; gr = bn + (s - 8) * 16 + l16; }
        sp[t] = base + (size_t)gr * TN + kbase + quad * 8;
    }
    f16* dseg = lds + wave * 4 * 512;
    const f16* rdb = lds + lane * 8;

    f32x4 acc[4][4];
#pragma unroll
    for (int i = 0; i < 4; ++i)
#pragma unroll
        for (int j = 0; j < 4; ++j) acc[i][j] = (f32x4){0.f, 0.f, 0.f, 0.f};

    for (int step = 0; step < 16; ++step) {
        __syncthreads();
#pragma unroll
        for (int t = 0; t < 4; ++t) { gll16(sp[t], dseg + t * 512); sp[t] += 32; }
        __syncthreads();

        f16x8 bf[4], af[4];
#pragma unroll
        for (int j = 0; j < 4; ++j) bf[j] = *(const f16x8*)(rdb + (8 + (wc >> 4) + j) * 512);
#pragma unroll
        for (int i = 0; i < 4; ++i) af[i] = *(const f16x8*)(rdb + ((wr >> 4) + i) * 512);
#pragma unroll
        for (int i = 0; i < 4; ++i)
#pragma unroll
            for (int j = 0; j < 4; ++j) acc[i][j] = MFMA16(af[i], bf[j], acc[i][j]);
    }
#pragma unroll
    for (int i = 0; i < 4; ++i)
#pragma unroll
        for (int j = 0; j < 4; ++j) {
            int row = bm + wr + i * 16 + quad * 4;
            int col = bn + wc + j * 16 + l16;
            float* p = C + (size_t)row * TN + col;
#pragma unroll
            for (int r = 0; r < 4; ++r) atomicAdd(p + (size_t)r * TN, acc[i][j][r]);
        }
}

// ---------------- softmax (fp32 in, fp16 P out) ----------------
__global__ void softmax_kernel(const float* __restrict__ S, f16* __restrict__ P) {
    __shared__ float red[256];
    const int row = blockIdx.x, tid = threadIdx.x;
    const float* s = S + (size_t)row * TN;
    float m = -3.4e38f;
    for (int c = tid; c < TN; c += 256) m = fmaxf(m, s[c]);
    red[tid] = m; __syncthreads();
    for (int st = 128; st > 0; st >>= 1) { if (tid < st) red[tid] = fmaxf(red[tid], red[tid + st]); __syncthreads(); }
    m = red[0]; __syncthreads();
    float sum = 0.f;
    for (int c = tid; c < TN; c += 256) sum += expf(s[c] - m);
    red[tid] = sum; __syncthreads();
    for (int st = 128; st > 0; st >>= 1) { if (tid < st) red[tid] += red[tid + st]; __syncthreads(); }
    float inv = 1.f / red[0];
    f16* p = P + (size_t)row * TN;
    for (int c = tid; c < TN; c += 256) p[c] = (f16)(expf(s[c] - m) * inv);
}

extern "C" void kernel_launch(void* const* d_in, const int* in_sizes, int n_in,
                              void* d_out, int out_size, void* d_ws, size_t ws_size,
                              hipStream_t stream) {
    const float* x = (const float*)d_in[0];
    const float* q = (const float*)d_in[1];
    const float* k = (const float*)d_in[2];
    const float* v = (const float*)d_in[3];
    float* out = (float*)d_out;
    const size_t M = (size_t)TN * TN;

    float* W1 = (float*)d_ws;
    float* W2 = W1 + M;
    f16* pl = (f16*)(W2 + M);
    f16 *x0 = pl,         *x1 = pl + M;
    f16 *q0 = pl + 2 * M, *q1 = pl + 3 * M;
    f16 *k0 = pl + 4 * M, *k1 = pl + 5 * M;
    f16 *v0 = pl + 6 * M;
    f16 *a0 = q0, *a1 = q1;
    f16 *b0 = k0, *b1 = k1;
    f16 *p0 = x1, *c0 = x0;

    dim3 bs(256);
    dim3 gsplit(TN * TN / 4 / 256);
    dim3 gt(TN / 64, TN / 64);
    dim3 gg(TN / 128, TN / 128, 4);   // 1024 blocks, 4/CU

    hipMemsetAsync(d_out, 0, M * 4, stream);
    hipLaunchKernelGGL(split2_kernel,  gsplit, bs, 0, stream, x, x0, x1);
    hipLaunchKernelGGL(split2t_kernel, gt,     bs, 0, stream, q, q0, q1);
    hipLaunchKernelGGL(gemm3_f16, gg, bs, 0, stream, x0, x1, q0, q1, out);
    hipMemsetAsync(W1, 0, M * 4, stream);
    hipLaunchKernelGGL(split2t_kernel, gt, bs, 0, stream, k, k0, k1);
    hipLaunchKernelGGL(gemm3_f16, gg, bs, 0, stream, x0, x1, k0, k1, W1);
    hipLaunchKernelGGL(split2_kernel,  gsplit, bs, 0, stream, out, a0, a1);
    hipLaunchKernelGGL(split2t_kernel, gt,     bs, 0, stream, W1, b0, b1);
    hipMemsetAsync(W2, 0, M * 4, stream);
    hipLaunchKernelGGL(gemm3_f16, gg, bs, 0, stream, a0, a1, b0, b1, W2);
    hipLaunchKernelGGL(softmax_kernel, dim3(TN), bs, 0, stream, W2, p0);
    hipLaunchKernelGGL(cast1t_kernel, gt, bs, 0, stream, v, v0);
    hipMemsetAsync(W1, 0, M * 4, stream);
    hipLaunchKernelGGL(gemm1_f16, gg, bs, 0, stream, x0, v0, W1);
    hipLaunchKernelGGL(cast1t_kernel, gt, bs, 0, stream, W1, c0);
    hipMemsetAsync(d_out, 0, M * 4, stream);
    hipLaunchKernelGGL(gemm1_f16, gg, bs, 0, stream, p0, c0, out);
}

// Round 7
// 753.791 us; speedup vs baseline: 2.0800x; 2.0800x over previous
//
#include <hip/hip_runtime.h>
#include <stdint.h>

// softmax((x@q)@(x@k)) @ (x@v), N=2048, fp32 in/out.
// R7: barrier-free flat GEMM. Planes are stored K-contiguous in exact MFMA
// fragment layout, so fragments are loaded global->VGPR directly (coalesced
// dwordx4, 16 fully-used 64B lines per wave-instr). No LDS, no __syncthreads:
// each wave pipelines its own K-loop; compiler hoists loads with fine-grained
// vmcnt. z=2 K-split with atomicAdd (benign at z=2 per R5 counters; z=4+DMA
// was the R6 catastrophe - reverted). Numerics unchanged: fp16 2-term split,
// 3 products (t0t0 + 2^-12*(t0t1'+t1't0)), absmax 1.0 across R4-R6.

#define TN 2048

typedef float f32x4 __attribute__((ext_vector_type(4)));
typedef _Float16 f16;
typedef f16 f16x8 __attribute__((ext_vector_type(8)));
typedef f16 f16x4 __attribute__((ext_vector_type(4)));

#define MFMA16(a, b, c) __builtin_amdgcn_mfma_f32_16x16x32_f16(a, b, c, 0, 0, 0)

// ---------------- split kernels: a ~= t0 + t1'/4096 ----------------
__global__ void split2_kernel(const float* __restrict__ in,
                              f16* __restrict__ t0, f16* __restrict__ t1) {
    int i = (blockIdx.x * 256 + threadIdx.x) * 4;
    f32x4 f = *(const f32x4*)(in + i);
    f16x4 o0, o1;
#pragma unroll
    for (int e = 0; e < 4; ++e) {
        float a = f[e];
        f16 h0 = (f16)a;
        float r = (a - (float)h0) * 4096.f;
        o0[e] = h0; o1[e] = (f16)r;
    }
    *(f16x4*)(t0 + i) = o0; *(f16x4*)(t1 + i) = o1;
}

__global__ void split2t_kernel(const float* __restrict__ in,
                               f16* __restrict__ t0, f16* __restrict__ t1) {
    __shared__ f16 s0[64][68], s1[64][68];
    int bc = blockIdx.x * 64, br = blockIdx.y * 64;
    int tx = threadIdx.x & 15, ty = threadIdx.x >> 4;
#pragma unroll
    for (int rr = 0; rr < 64; rr += 16) {
        int r = rr + ty;
        f32x4 f = *(const f32x4*)(in + (size_t)(br + r) * TN + bc + tx * 4);
#pragma unroll
        for (int e = 0; e < 4; ++e) {
            float a = f[e];
            f16 h0 = (f16)a;
            float rr2 = (a - (float)h0) * 4096.f;
            s0[tx * 4 + e][r] = h0; s1[tx * 4 + e][r] = (f16)rr2;
        }
    }
    __syncthreads();
#pragma unroll
    for (int rr = 0; rr < 64; rr += 16) {
        int c = rr + ty;
        f16x4 o0, o1;
#pragma unroll
        for (int e = 0; e < 4; ++e) { o0[e] = s0[c][tx*4+e]; o1[e] = s1[c][tx*4+e]; }
        size_t off = (size_t)(bc + c) * TN + br + tx * 4;
        *(f16x4*)(t0 + off) = o0; *(f16x4*)(t1 + off) = o1;
    }
}

__global__ void cast1t_kernel(const float* __restrict__ in, f16* __restrict__ t0) {
    __shared__ f16 s0[64][68];
    int bc = blockIdx.x * 64, br = blockIdx.y * 64;
    int tx = threadIdx.x & 15, ty = threadIdx.x >> 4;
#pragma unroll
    for (int rr = 0; rr < 64; rr += 16) {
        int r = rr + ty;
        f32x4 f = *(const f32x4*)(in + (size_t)(br + r) * TN + bc + tx * 4);
#pragma unroll
        for (int e = 0; e < 4; ++e) s0[tx * 4 + e][r] = (f16)f[e];
    }
    __syncthreads();
#pragma unroll
    for (int rr = 0; rr < 64; rr += 16) {
        int c = rr + ty;
        f16x4 o0;
#pragma unroll
        for (int e = 0; e < 4; ++e) o0[e] = s0[c][tx*4+e];
        *(f16x4*)(t0 + (size_t)(bc + c) * TN + br + tx * 4) = o0;
    }
}

// ---------------- flat 3-product GEMM: no LDS, no barriers ----------------
// Wave tile 64x64 (4x4 of 16x16x32). Frag loads straight from global:
// A row = bm+wr+i*16+l16, k = quad*8.. ; same for Bt. Unroll-by-8 K-steps so
// in-loop loads use immediate offsets; offsets advance once per 8 steps.
__global__ __launch_bounds__(256, 2) void gemm3_flat(
    const f16* __restrict__ a0p, const f16* __restrict__ a1p,
    const f16* __restrict__ b0p, const f16* __restrict__ b1p,
    float* __restrict__ C) {
    const int tid = threadIdx.x;
    const int wave = tid >> 6, lane = tid & 63;
    const int wr = (wave >> 1) * 64, wc = (wave & 1) * 64;
    const int quad = lane >> 4, l16 = lane & 15;
    const int bm = blockIdx.y * 128, bn = blockIdx.x * 128;
    const int kbase = blockIdx.z * 1024;

    unsigned offA[4], offB[4];
#pragma unroll
    for (int i = 0; i < 4; ++i) {
        offA[i] = (unsigned)(bm + wr + i * 16 + l16) * TN + kbase + quad * 8;
        offB[i] = (unsigned)(bn + wc + i * 16 + l16) * TN + kbase + quad * 8;
    }

    f32x4 acc1[4][4], acc2[4][4];
#pragma unroll
    for (int i = 0; i < 4; ++i)
#pragma unroll
        for (int j = 0; j < 4; ++j) {
            acc1[i][j] = (f32x4){0.f, 0.f, 0.f, 0.f};
            acc2[i][j] = (f32x4){0.f, 0.f, 0.f, 0.f};
        }

    for (int kk = 0; kk < 4; ++kk) {         // 4 x 8 steps = 32 steps (K=1024)
#pragma unroll
        for (int s = 0; s < 8; ++s) {
            const int d = s * 32;            // elements; folds into imm offset
            f16x8 a0f[4], a1f[4], b0f[4], b1f[4];
#pragma unroll
            for (int i = 0; i < 4; ++i) {
                a0f[i] = *(const f16x8*)(a0p + offA[i] + d);
                a1f[i] = *(const f16x8*)(a1p + offA[i] + d);
            }
#pragma unroll
            for (int j = 0; j < 4; ++j) {
                b0f[j] = *(const f16x8*)(b0p + offB[j] + d);
                b1f[j] = *(const f16x8*)(b1p + offB[j] + d);
            }
#pragma unroll
            for (int i = 0; i < 4; ++i)
#pragma unroll
                for (int j = 0; j < 4; ++j) {
                    acc1[i][j] = MFMA16(a0f[i], b0f[j], acc1[i][j]);
                    acc2[i][j] = MFMA16(a0f[i], b1f[j], acc2[i][j]);
                    acc2[i][j] = MFMA16(a1f[i], b0f[j], acc2[i][j]);
                }
        }
#pragma unroll
        for (int i = 0; i < 4; ++i) { offA[i] += 256; offB[i] += 256; }
    }

    const float sc = 1.f / 4096.f;
#pragma unroll
    for (int i = 0; i < 4; ++i)
#pragma unroll
        for (int j = 0; j < 4; ++j) {
            int row = bm + wr + i * 16 + quad * 4;
            int col = bn + wc + j * 16 + l16;
            float* p = C + (size_t)row * TN + col;
#pragma unroll
            for (int r = 0; r < 4; ++r)
                atomicAdd(p + (size_t)r * TN, acc1[i][j][r] + acc2[i][j][r] * sc);
        }
}

// ---------------- flat single-product GEMM ----------------
__global__ __launch_bounds__(256, 2) void gemm1_flat(
    const f16* __restrict__ A, const f16* __restrict__ Bt,
    float* __restrict__ C) {
    const int tid = threadIdx.x;
    const int wave = tid >> 6, lane = tid & 63;
    const int wr = (wave >> 1) * 64, wc = (wave & 1) * 64;
    const int quad = lane >> 4, l16 = lane & 15;
    const int bm = blockIdx.y * 128, bn = blockIdx.x * 128;
    const int kbase = blockIdx.z * 1024;

    unsigned offA[4], offB[4];
#pragma unroll
    for (int i = 0; i < 4; ++i) {
        offA[i] = (unsigned)(bm + wr + i * 16 + l16) * TN + kbase + quad * 8;
        offB[i] = (unsigned)(bn + wc + i * 16 + l16) * TN + kbase + quad * 8;
    }

    f32x4 acc[4][4];
#pragma unroll
    for (int i = 0; i < 4; ++i)
#pragma unroll
        for (int j = 0; j < 4; ++j) acc[i][j] = (f32x4){0.f, 0.f, 0.f, 0.f};

    for (int kk = 0; kk < 4; ++kk) {
#pragma unroll
        for (int s = 0; s < 8; ++s) {
            const int d = s * 32;
            f16x8 af[4], bf[4];
#pragma unroll
            for (int i = 0; i < 4; ++i) af[i] = *(const f16x8*)(A + offA[i] + d);
#pragma unroll
            for (int j = 0; j < 4; ++j) bf[j] = *(const f16x8*)(Bt + offB[j] + d);
#pragma unroll
            for (int i = 0; i < 4; ++i)
#pragma unroll
                for (int j = 0; j < 4; ++j)
                    acc[i][j] = MFMA16(af[i], bf[j], acc[i][j]);
        }
#pragma unroll
        for (int i = 0; i < 4; ++i) { offA[i] += 256; offB[i] += 256; }
    }
#pragma unroll
    for (int i = 0; i < 4; ++i)
#pragma unroll
        for (int j = 0; j < 4; ++j) {
            int row = bm + wr + i * 16 + quad * 4;
            int col = bn + wc + j * 16 + l16;
            float* p = C + (size_t)row * TN + col;
#pragma unroll
            for (int r = 0; r < 4; ++r) atomicAdd(p + (size_t)r * TN, acc[i][j][r]);
        }
}

// ---------------- softmax (fp32 in, fp16 P out) ----------------
__global__ void softmax_kernel(const float* __restrict__ S, f16* __restrict__ P) {
    __shared__ float red[256];
    const int row = blockIdx.x, tid = threadIdx.x;
    const float* s = S + (size_t)row * TN;
    float m = -3.4e38f;
    for (int c = tid; c < TN; c += 256) m = fmaxf(m, s[c]);
    red[tid] = m; __syncthreads();
    for (int st = 128; st > 0; st >>= 1) { if (tid < st) red[tid] = fmaxf(red[tid], red[tid + st]); __syncthreads(); }
    m = red[0]; __syncthreads();
    float sum = 0.f;
    for (int c = tid; c < TN; c += 256) sum += expf(s[c] - m);
    red[tid] = sum; __syncthreads();
    for (int st = 128; st > 0; st >>= 1) { if (tid < st) red[tid] += red[tid + st]; __syncthreads(); }
    float inv = 1.f / red[0];
    f16* p = P + (size_t)row * TN;
    for (int c = tid; c < TN; c += 256) p[c] = (f16)(expf(s[c] - m) * inv);
}

extern "C" void kernel_launch(void* const* d_in, const int* in_sizes, int n_in,
                              void* d_out, int out_size, void* d_ws, size_t ws_size,
                              hipStream_t stream) {
    const float* x = (const float*)d_in[0];
    const float* q = (const float*)d_in[1];
    const float* k = (const float*)d_in[2];
    const float* v = (const float*)d_in[3];
    float* out = (float*)d_out;
    const size_t M = (size_t)TN * TN;

    float* W1 = (float*)d_ws;
    float* W2 = W1 + M;
    f16* pl = (f16*)(W2 + M);
    f16 *x0 = pl,         *x1 = pl + M;
    f16 *q0 = pl + 2 * M, *q1 = pl + 3 * M;
    f16 *k0 = pl + 4 * M, *k1 = pl + 5 * M;
    f16 *v0 = pl + 6 * M;
    f16 *a0 = q0, *a1 = q1;
    f16 *b0 = k0, *b1 = k1;
    f16 *p0 = x1, *c0 = x0;

    dim3 bs(256);
    dim3 gsplit(TN * TN / 4 / 256);
    dim3 gt(TN / 64, TN / 64);
    dim3 gg(TN / 128, TN / 128, 2);   // 512 blocks, 2/CU, z = K-split

    hipMemsetAsync(d_out, 0, M * 4, stream);
    hipLaunchKernelGGL(split2_kernel,  gsplit, bs, 0, stream, x, x0, x1);
    hipLaunchKernelGGL(split2t_kernel, gt,     bs, 0, stream, q, q0, q1);
    hipLaunchKernelGGL(gemm3_flat, gg, bs, 0, stream, x0, x1, q0, q1, out);
    hipMemsetAsync(W1, 0, M * 4, stream);
    hipLaunchKernelGGL(split2t_kernel, gt, bs, 0, stream, k, k0, k1);
    hipLaunchKernelGGL(gemm3_flat, gg, bs, 0, stream, x0, x1, k0, k1, W1);
    hipLaunchKernelGGL(split2_kernel,  gsplit, bs, 0, stream, out, a0, a1);
    hipLaunchKernelGGL(split2t_kernel, gt,     bs, 0, stream, W1, b0, b1);
    hipMemsetAsync(W2, 0, M * 4, stream);
    hipLaunchKernelGGL(gemm3_flat, gg, bs, 0, stream, a0, a1, b0, b1, W2);
    hipLaunchKernelGGL(softmax_kernel, dim3(TN), bs, 0, stream, W2, p0);
    hipLaunchKernelGGL(cast1t_kernel, gt, bs, 0, stream, v, v0);
    hipMemsetAsync(W1, 0, M * 4, stream);
    hipLaunchKernelGGL(gemm1_flat, gg, bs, 0, stream, x0, v0, W1);
    hipLaunchKernelGGL(cast1t_kernel, gt, bs, 0, stream, W1, c0);
    hipMemsetAsync(d_out, 0, M * 4, stream);
    hipLaunchKernelGGL(gemm1_flat, gg, bs, 0, stream, p0, c0, out);
}